// Round 2
// baseline (225.234 us; speedup 1.0000x reference)
//
#include <hip/hip_runtime.h>

#define FIELDS  100000
#define FACTORS 16
#define BATCH   1024
#define BT      4            // batch rows per block
#define NCHUNK  8            // field chunks (one per XCD via round-robin)
#define FPC     (FIELDS / NCHUNK)   // 12500 fields per chunk
#define BLOCK   256
#define FPT     4            // fields per thread per iter (int4 x0 load)

// Thread t: half = t&1 (8 factors), p = t>>1 (field group of FPT fields).
// Per iter: 4 x int4 x0 loads (16B/lane), 8 x dwordx4 W loads,
// 4 rows x 4 fields x 9 FMAs with 4-deep fma chains.
__global__ __launch_bounds__(BLOCK, 4) void fm_partial(
    const int* __restrict__ x0, const float* __restrict__ W,
    float* __restrict__ ws)
{
    const int t     = threadIdx.x;
    const int bid   = blockIdx.x;
    const int bg    = bid >> 3;              // 0..255
    const int chunk = bid & (NCHUNK - 1);    // 0..7 -> XCD-local W slice
    const int b0    = bg * BT;
    const int fbeg  = chunk * FPC;
    const int fend  = fbeg + FPC;
    const int p     = t >> 1;                // 0..127
    const int half  = t & 1;

    float acc[BT][8];
    float qac[BT];
#pragma unroll
    for (int r = 0; r < BT; ++r) {
        qac[r] = 0.f;
#pragma unroll
        for (int j = 0; j < 8; ++j) acc[r][j] = 0.f;
    }

    const int* xb = x0 + (size_t)b0 * FIELDS;

    for (int f0 = fbeg + FPT * p; f0 < fend; f0 += FPT * (BLOCK / 2)) {
        // ---- W: 4 rows x 8 factors (this thread's half) ----
        const float* wp = W + (size_t)f0 * FACTORS + half * 8;
        float4 wa[FPT], wb[FPT];
#pragma unroll
        for (int i = 0; i < FPT; ++i) {
            wa[i] = *reinterpret_cast<const float4*>(wp + i * FACTORS);
            wb[i] = *reinterpret_cast<const float4*>(wp + i * FACTORS + 4);
        }
        float ssq[FPT];
#pragma unroll
        for (int i = 0; i < FPT; ++i) {
            ssq[i] = wa[i].x*wa[i].x + wa[i].y*wa[i].y + wa[i].z*wa[i].z + wa[i].w*wa[i].w
                   + wb[i].x*wb[i].x + wb[i].y*wb[i].y + wb[i].z*wb[i].z + wb[i].w*wb[i].w;
        }
        // ---- x0: BT rows x 4 fields ----
        int4 xv[BT];
#pragma unroll
        for (int r = 0; r < BT; ++r)
            xv[r] = *reinterpret_cast<const int4*>(xb + (size_t)r * FIELDS + f0);

#pragma unroll
        for (int r = 0; r < BT; ++r) {
            const float m0 = (xv[r].x > 0) ? 1.0f : 0.0f;
            const float m1 = (xv[r].y > 0) ? 1.0f : 0.0f;
            const float m2 = (xv[r].z > 0) ? 1.0f : 0.0f;
            const float m3 = (xv[r].w > 0) ? 1.0f : 0.0f;
            qac[r] = fmaf(m0, ssq[0], fmaf(m1, ssq[1], fmaf(m2, ssq[2], fmaf(m3, ssq[3], qac[r]))));
            const float wj0[8] = {wa[0].x,wa[0].y,wa[0].z,wa[0].w,wb[0].x,wb[0].y,wb[0].z,wb[0].w};
            const float wj1[8] = {wa[1].x,wa[1].y,wa[1].z,wa[1].w,wb[1].x,wb[1].y,wb[1].z,wb[1].w};
            const float wj2[8] = {wa[2].x,wa[2].y,wa[2].z,wa[2].w,wb[2].x,wb[2].y,wb[2].z,wb[2].w};
            const float wj3[8] = {wa[3].x,wa[3].y,wa[3].z,wa[3].w,wb[3].x,wb[3].y,wb[3].z,wb[3].w};
#pragma unroll
            for (int j = 0; j < 8; ++j)
                acc[r][j] = fmaf(m0, wj0[j], fmaf(m1, wj1[j], fmaf(m2, wj2[j], fmaf(m3, wj3[j], acc[r][j]))));
        }
    }

    // ---- wave-level reduce ----
    // s: sum over same-parity lanes (same factor-half): xor 2..32
    // q: sum over all 64 lanes (combines both halves' ssq): xor 1..32
#pragma unroll
    for (int r = 0; r < BT; ++r) {
#pragma unroll
        for (int off = 2; off < 64; off <<= 1) {
#pragma unroll
            for (int j = 0; j < 8; ++j)
                acc[r][j] += __shfl_xor(acc[r][j], off);
        }
#pragma unroll
        for (int off = 1; off < 64; off <<= 1)
            qac[r] += __shfl_xor(qac[r], off);
    }

    // ---- cross-wave combine, then non-atomic store to private slot ----
    __shared__ float red[4][BT][17];
    const int wave = t >> 6;
    const int lane = t & 63;
    if (lane < 2) {
#pragma unroll
        for (int r = 0; r < BT; ++r) {
#pragma unroll
            for (int j = 0; j < 8; ++j)
                red[wave][r][lane * 8 + j] = acc[r][j];
            if (lane == 0) red[wave][r][16] = qac[r];
        }
    }
    __syncthreads();
    if (t < BT * 17) {
        const int r = t / 17;
        const int j = t % 17;
        const float v = red[0][r][j] + red[1][r][j] + red[2][r][j] + red[3][r][j];
        // layout: ws[b][chunk][j], b-major for fm_final coalescing
        ws[((size_t)(b0 + r) * NCHUNK + chunk) * 17 + j] = v;
    }
}

__global__ __launch_bounds__(BLOCK) void fm_final(
    const float* __restrict__ ws, float* __restrict__ out)
{
    const int b = blockIdx.x * BLOCK + threadIdx.x;
    if (b < BATCH) {
        const float* pbase = ws + (size_t)b * NCHUNK * 17;
        float s[17];
#pragma unroll
        for (int j = 0; j < 17; ++j) s[j] = 0.f;
#pragma unroll
        for (int c = 0; c < NCHUNK; ++c)
#pragma unroll
            for (int j = 0; j < 17; ++j) s[j] += pbase[c * 17 + j];
        float ss = 0.f;
#pragma unroll
        for (int k = 0; k < FACTORS; ++k) ss += s[k] * s[k];
        out[b] = 0.5f * (ss - s[16]);
    }
}

extern "C" void kernel_launch(void* const* d_in, const int* in_sizes, int n_in,
                              void* d_out, int out_size, void* d_ws, size_t ws_size,
                              hipStream_t stream)
{
    const int*   x0 = (const int*)d_in[0];
    const float* W  = (const float*)d_in[1];
    float* out = (float*)d_out;
    float* ws  = (float*)d_ws;   // BATCH x NCHUNK x 17 floats, every slot written

    fm_partial<<<dim3((BATCH / BT) * NCHUNK), dim3(BLOCK), 0, stream>>>(x0, W, ws);
    fm_final<<<dim3((BATCH + BLOCK - 1) / BLOCK), dim3(BLOCK), 0, stream>>>(ws, out);
}

// Round 4
// 143.805 us; speedup vs baseline: 1.5662x; 1.5662x over previous
//
#include <hip/hip_runtime.h>

#define FIELDS  100000
#define FACTORS 16
#define BATCH   1024
#define BT      8            // batch rows per block
#define NCHUNK  8            // field chunks, chunk == bid%8 -> XCD-pinned W slice
#define FPC     (FIELDS / NCHUNK)   // 12500 fields per chunk
#define BLOCK   256
#define STRIDE  (BLOCK / 2)  // 128 fields per block-iteration

// Thread t: half = t&1 (8 factors), p = t>>1 (field lane).
// Per iter: 2 W float4 loads (L2-warm), 8 scalar x0 loads prefetched 2 deep,
// 8 rows x (1 q-fma + 8 acc-fma). Register budget ~115 -> 4 waves/SIMD.
__global__ __launch_bounds__(BLOCK, 4) void fm_partial(
    const int* __restrict__ x0, const float* __restrict__ W,
    float* __restrict__ ws)
{
    const int t     = threadIdx.x;
    const int bid   = blockIdx.x;
    const int bg    = bid >> 3;              // 0..127
    const int chunk = bid & (NCHUNK - 1);    // 0..7
    const int b0    = bg * BT;
    const int fbeg  = chunk * FPC;
    const int fend  = fbeg + FPC;
    const int p     = t >> 1;                // 0..127
    const int half  = t & 1;

    float acc[BT][8];
    float qac[BT];
#pragma unroll
    for (int r = 0; r < BT; ++r) {
        qac[r] = 0.f;
#pragma unroll
        for (int j = 0; j < 8; ++j) acc[r][j] = 0.f;
    }

    const int*   xb = x0 + (size_t)b0 * FIELDS;
    const float* Wh = W + half * 8;

    const int f0 = fbeg + p;

    // ---- software pipeline: x0 prefetched 2 iterations deep ----
    int xc[BT], xm[BT], xn[BT];
    {
        const int f1 = (f0 + STRIDE < fend) ? f0 + STRIDE : f0;
#pragma unroll
        for (int r = 0; r < BT; ++r) xc[r] = xb[(size_t)r * FIELDS + f0];
#pragma unroll
        for (int r = 0; r < BT; ++r) xm[r] = xb[(size_t)r * FIELDS + f1];
    }

    for (int f = f0; f < fend; f += STRIDE) {
        // current W (L2-warm after first sweep; stall covered by sibling waves)
        const float* wp = Wh + (size_t)f * FACTORS;
        const float4 wa = *reinterpret_cast<const float4*>(wp);
        const float4 wb = *reinterpret_cast<const float4*>(wp + 4);

        // issue x0 prefetch for f+2*STRIDE (clamped; tail value never consumed)
        const int fx = (f + 2 * STRIDE < fend) ? f + 2 * STRIDE : f0;
#pragma unroll
        for (int r = 0; r < BT; ++r) xn[r] = xb[(size_t)r * FIELDS + fx];

        // ssq of THIS HALF's 8 factors; the all-lane q-reduce below combines
        // half 0 (factors 0-7) and half 1 (factors 8-15) exactly once.
        float ssq;
        ssq = wa.x * wa.x;
        ssq = fmaf(wa.y, wa.y, ssq);
        ssq = fmaf(wa.z, wa.z, ssq);
        ssq = fmaf(wa.w, wa.w, ssq);
        ssq = fmaf(wb.x, wb.x, ssq);
        ssq = fmaf(wb.y, wb.y, ssq);
        ssq = fmaf(wb.z, wb.z, ssq);
        ssq = fmaf(wb.w, wb.w, ssq);

#pragma unroll
        for (int r = 0; r < BT; ++r) {
            const float m = (xc[r] > 0) ? 1.0f : 0.0f;
            qac[r]    = fmaf(m, ssq,  qac[r]);
            acc[r][0] = fmaf(m, wa.x, acc[r][0]);
            acc[r][1] = fmaf(m, wa.y, acc[r][1]);
            acc[r][2] = fmaf(m, wa.z, acc[r][2]);
            acc[r][3] = fmaf(m, wa.w, acc[r][3]);
            acc[r][4] = fmaf(m, wb.x, acc[r][4]);
            acc[r][5] = fmaf(m, wb.y, acc[r][5]);
            acc[r][6] = fmaf(m, wb.z, acc[r][6]);
            acc[r][7] = fmaf(m, wb.w, acc[r][7]);
        }

        // rotate pipeline (static indices only)
#pragma unroll
        for (int r = 0; r < BT; ++r) { xc[r] = xm[r]; xm[r] = xn[r]; }
    }

    // ---- wave-level reduce ----
    // s: sum over same-parity lanes (same factor-half): xor 2..32
    // q: sum over ALL 64 lanes: half-0 lanes hold factors 0-7 ssq-sums,
    //    half-1 lanes hold factors 8-15 -> together the full q, once.
#pragma unroll
    for (int r = 0; r < BT; ++r) {
#pragma unroll
        for (int off = 2; off < 64; off <<= 1) {
#pragma unroll
            for (int j = 0; j < 8; ++j)
                acc[r][j] += __shfl_xor(acc[r][j], off);
        }
#pragma unroll
        for (int off = 1; off < 64; off <<= 1)
            qac[r] += __shfl_xor(qac[r], off);
    }

    // ---- cross-wave combine, non-atomic private slots ----
    __shared__ float red[4][BT][17];
    const int wave = t >> 6;
    const int lane = t & 63;
    if (lane < 2) {
#pragma unroll
        for (int r = 0; r < BT; ++r) {
#pragma unroll
            for (int j = 0; j < 8; ++j)
                red[wave][r][lane * 8 + j] = acc[r][j];
            if (lane == 0) red[wave][r][16] = qac[r];
        }
    }
    __syncthreads();
    if (t < BT * 17) {
        const int r = t / 17;
        const int j = t % 17;
        const float v = red[0][r][j] + red[1][r][j] + red[2][r][j] + red[3][r][j];
        ws[((size_t)(b0 + r) * NCHUNK + chunk) * 17 + j] = v;
    }
}

__global__ __launch_bounds__(BLOCK) void fm_final(
    const float* __restrict__ ws, float* __restrict__ out)
{
    const int b = blockIdx.x * BLOCK + threadIdx.x;
    if (b < BATCH) {
        const float* pbase = ws + (size_t)b * NCHUNK * 17;
        float s[17];
#pragma unroll
        for (int j = 0; j < 17; ++j) s[j] = 0.f;
#pragma unroll
        for (int c = 0; c < NCHUNK; ++c)
#pragma unroll
            for (int j = 0; j < 17; ++j) s[j] += pbase[c * 17 + j];
        float ss = 0.f;
#pragma unroll
        for (int k = 0; k < FACTORS; ++k) ss += s[k] * s[k];
        out[b] = 0.5f * (ss - s[16]);
    }
}

extern "C" void kernel_launch(void* const* d_in, const int* in_sizes, int n_in,
                              void* d_out, int out_size, void* d_ws, size_t ws_size,
                              hipStream_t stream)
{
    const int*   x0 = (const int*)d_in[0];
    const float* W  = (const float*)d_in[1];
    float* out = (float*)d_out;
    float* ws  = (float*)d_ws;   // BATCH x NCHUNK x 17 floats, every slot written

    fm_partial<<<dim3((BATCH / BT) * NCHUNK), dim3(BLOCK), 0, stream>>>(x0, W, ws);
    fm_final<<<dim3((BATCH + BLOCK - 1) / BLOCK), dim3(BLOCK), 0, stream>>>(ws, out);
}

// Round 5
// 141.101 us; speedup vs baseline: 1.5963x; 1.0192x over previous
//
#include <hip/hip_runtime.h>

#define FIELDS  100000
#define FACTORS 16
#define BATCH   1024
#define BT      8                      // batch rows per block
#define NCHUNK  8                      // field chunks; chunk == bid&7 -> XCD-pinned W slice
#define FPC     (FIELDS / NCHUNK)      // 12500 fields per chunk
#define BLOCK   256
#define TF      128                    // fields per tile
#define NT      ((FPC + TF - 1) / TF)  // 98 tiles (last tile = 84 valid fields)
#define NBUF    3                      // pipeline depth

typedef __attribute__((address_space(1))) const void gvoid;
typedef __attribute__((address_space(3))) void lvoid;

// Thread t: factor-quarter qr = t&3, field slot p = t>>2 (64 slots, 2 passes/tile).
// Streams: x0 tile [8][128] int (4KB) + W tile [128][16] f32 (8KB) staged via
// global_load_lds, 3-deep, counted vmcnt(6) — never drained in the main loop.
__global__ __launch_bounds__(BLOCK, 4) void fm_partial(
    const int* __restrict__ x0, const float* __restrict__ W,
    float* __restrict__ ws)
{
    __shared__ int   xbuf[NBUF][BT][TF];         // 12 KB
    __shared__ float wbuf[NBUF][TF * FACTORS];   // 24 KB
    __shared__ float red[4][BT][17];             // 2.1 KB

    const int t     = threadIdx.x;
    const int bid   = blockIdx.x;
    const int bg    = bid >> 3;               // 0..127
    const int chunk = bid & (NCHUNK - 1);     // 0..7
    const int b0    = bg * BT;
    const int fbeg  = chunk * FPC;

    const int qr = t & 3;                     // factor quarter (4 factors)
    const int p  = t >> 2;                    // field slot 0..63

    float acc[BT][4];
    float qac[BT];
#pragma unroll
    for (int r = 0; r < BT; ++r) {
        qac[r] = 0.f;
#pragma unroll
        for (int j = 0; j < 4; ++j) acc[r][j] = 0.f;
    }

    // ---- staging geometry (per-lane global src, lane-linear LDS dest) ----
    const char* x0b = (const char*)x0;
    const char* Wb  = (const char*)W;
    const size_t X0MAX = (size_t)BATCH * FIELDS * 4 - 16;   // clamp: stay in-bounds
    const size_t WMAX  = (size_t)FIELDS * FACTORS * 4 - 16;

    const int    srow  = t >> 5;              // x0 row this thread stages (2 rows/wave)
    const size_t xbase = ((size_t)(b0 + srow) * FIELDS + fbeg) * 4 + (size_t)(t & 31) * 16;
    const size_t wbase = (size_t)fbeg * 64 + (size_t)t * 16;

    auto STAGE = [&](int buf, int tile) {
        size_t xo = xbase + (size_t)tile * (TF * 4);
        if (xo > X0MAX) xo = X0MAX;
        __builtin_amdgcn_global_load_lds((gvoid*)(x0b + xo),
            (lvoid*)((char*)&xbuf[buf][0][0] + t * 16), 16, 0, 0);
        size_t wo  = wbase + (size_t)tile * (TF * 64);
        size_t wo2 = wo + 4096;
        if (wo  > WMAX) wo  = WMAX;
        if (wo2 > WMAX) wo2 = WMAX;
        __builtin_amdgcn_global_load_lds((gvoid*)(Wb + wo),
            (lvoid*)((char*)&wbuf[buf][0] + t * 16), 16, 0, 0);
        __builtin_amdgcn_global_load_lds((gvoid*)(Wb + wo2),
            (lvoid*)((char*)&wbuf[buf][0] + 4096 + t * 16), 16, 0, 0);
    };

    STAGE(0, 0);
    STAGE(1, 1);

    for (int tile = 0; tile < NT; ++tile) {
        const int nb = tile + 2;
        if (nb < NT) {
            STAGE(nb % NBUF, nb);                       // 3 more in flight (<=9)
            asm volatile("s_waitcnt vmcnt(6)" ::: "memory");   // tile's 3 retired
        } else if (tile + 1 < NT) {
            asm volatile("s_waitcnt vmcnt(3)" ::: "memory");
        } else {
            asm volatile("s_waitcnt vmcnt(0)" ::: "memory");
        }
        __builtin_amdgcn_s_barrier();            // all waves' tile data in LDS
        __builtin_amdgcn_sched_barrier(0);       // no hoisting LDS reads above

        const int buf  = tile % NBUF;
        const int flim = FPC - tile * TF;        // valid fields this tile
#pragma unroll
        for (int pass = 0; pass < 2; ++pass) {
            const int  fld   = pass * 64 + p;
            const bool valid = (fld < flim);
            const float4 wv = *reinterpret_cast<const float4*>(
                &wbuf[buf][fld * FACTORS + qr * 4]);       // lane-linear b128
            float ssq = wv.x * wv.x;
            ssq = fmaf(wv.y, wv.y, ssq);
            ssq = fmaf(wv.z, wv.z, ssq);
            ssq = fmaf(wv.w, wv.w, ssq);
#pragma unroll
            for (int r = 0; r < BT; ++r) {
                const int   xv = xbuf[buf][r][fld];         // b32 broadcast
                const float m  = (valid && xv > 0) ? 1.0f : 0.0f;
                qac[r]    = fmaf(m, ssq,  qac[r]);
                acc[r][0] = fmaf(m, wv.x, acc[r][0]);
                acc[r][1] = fmaf(m, wv.y, acc[r][1]);
                acc[r][2] = fmaf(m, wv.z, acc[r][2]);
                acc[r][3] = fmaf(m, wv.w, acc[r][3]);
            }
        }
        __builtin_amdgcn_sched_barrier(0);       // keep compute before the fence
        __builtin_amdgcn_s_barrier();            // all done with buf before re-stage
    }

    // ---- wave reduce ----
    // acc: sum lanes with same qr (xor 4..32) -> lanes 0..3 hold factor quarters
    // q:   sum all 64 lanes (each lane's qac covers its fields x its quarter)
#pragma unroll
    for (int r = 0; r < BT; ++r) {
#pragma unroll
        for (int off = 4; off < 64; off <<= 1) {
#pragma unroll
            for (int j = 0; j < 4; ++j)
                acc[r][j] += __shfl_xor(acc[r][j], off);
        }
#pragma unroll
        for (int off = 1; off < 64; off <<= 1)
            qac[r] += __shfl_xor(qac[r], off);
    }

    const int wave = t >> 6;
    const int lane = t & 63;
    if (lane < 4) {
#pragma unroll
        for (int r = 0; r < BT; ++r) {
#pragma unroll
            for (int j = 0; j < 4; ++j)
                red[wave][r][lane * 4 + j] = acc[r][j];
            if (lane == 0) red[wave][r][16] = qac[r];
        }
    }
    __syncthreads();
    if (t < BT * 17) {
        const int r = t / 17;
        const int j = t % 17;
        const float v = red[0][r][j] + red[1][r][j] + red[2][r][j] + red[3][r][j];
        ws[((size_t)(b0 + r) * NCHUNK + chunk) * 17 + j] = v;
    }
}

__global__ __launch_bounds__(BLOCK) void fm_final(
    const float* __restrict__ ws, float* __restrict__ out)
{
    const int b = blockIdx.x * BLOCK + threadIdx.x;
    if (b < BATCH) {
        const float* pbase = ws + (size_t)b * NCHUNK * 17;
        float s[17];
#pragma unroll
        for (int j = 0; j < 17; ++j) s[j] = 0.f;
#pragma unroll
        for (int c = 0; c < NCHUNK; ++c)
#pragma unroll
            for (int j = 0; j < 17; ++j) s[j] += pbase[c * 17 + j];
        float ss = 0.f;
#pragma unroll
        for (int k = 0; k < FACTORS; ++k) ss += s[k] * s[k];
        out[b] = 0.5f * (ss - s[16]);
    }
}

extern "C" void kernel_launch(void* const* d_in, const int* in_sizes, int n_in,
                              void* d_out, int out_size, void* d_ws, size_t ws_size,
                              hipStream_t stream)
{
    const int*   x0 = (const int*)d_in[0];
    const float* W  = (const float*)d_in[1];
    float* out = (float*)d_out;
    float* ws  = (float*)d_ws;   // BATCH x NCHUNK x 17 floats, every slot written

    fm_partial<<<dim3((BATCH / BT) * NCHUNK), dim3(BLOCK), 0, stream>>>(x0, W, ws);
    fm_final<<<dim3((BATCH + BLOCK - 1) / BLOCK), dim3(BLOCK), 0, stream>>>(ws, out);
}